// Round 7
// baseline (1242.996 us; speedup 1.0000x reference)
//
#include <hip/hip_runtime.h>
#include <stdint.h>

// Problem constants
#define NB    16
#define NN    4096
#define NP    1024
#define NS    32
#define NGRP  (NB*NP)          // 16384 groups
#define CNT   524288.0         // B*K*S elements per channel for BN stats

typedef short  bf16x8 __attribute__((ext_vector_type(8)));
typedef float  f32x4  __attribute__((ext_vector_type(4)));

// ---------- bf16 helpers (RNE) ----------
__device__ __forceinline__ float bf2f(unsigned short u) {
    return __uint_as_float(((unsigned)u) << 16);
}
__device__ __forceinline__ unsigned short f2bf(float f) {
    unsigned u = __float_as_uint(f);
    unsigned r = u + 0x7fffu + ((u >> 16) & 1u);
    return (unsigned short)(r >> 16);
}
__device__ __forceinline__ bf16x8 as_bf(uint4 u) {
    union { uint4 a; bf16x8 b; } c; c.a = u; return c.b;
}

// u64 max with one DPP step (compare-select). VALU-only.
template <int CTRL, int RM>
__device__ __forceinline__ unsigned long long dppmax(unsigned long long k) {
    int lo = (int)(unsigned)k;
    int hi = (int)(k >> 32);
    int ml = __builtin_amdgcn_update_dpp(lo, lo, CTRL, RM, 0xf, false);
    int mh = __builtin_amdgcn_update_dpp(hi, hi, CTRL, RM, 0xf, false);
    unsigned long long m = ((unsigned long long)(unsigned)mh << 32) | (unsigned)ml;
    return m > k ? m : k;
}

// =====================================================================
// K1 (fused): blocks 0..15 = FPS (one per batch), blocks 16..255 = the
// per-point transform T (grid-stride over chunks; grid==256 so no T
// block ever shares a CU with an FPS block).
// FPS: 256 thr x 16 pts, exact arithmetic (no fma, ((xx+yy)+zz) order),
// key=(dist_bits<<32)|~n packs exact argmax-tie-lowest into u64 max.
// Round-7: candidate xyz embedded in the reduce slots — lane63 reads
// sxyz4[n_win] PRE-barrier (overlaps barrier skew) so the post-barrier
// path is one parallel LDS round (keys+xyz) + 3-level select, killing
// the dependent centroid read (was ~120 cyc on the serial chain).
// Slots are parity double-buffered; t=0 slot primed (key=~0 -> far=0).
// =====================================================================
__global__ __launch_bounds__(256, 1) void fps_t_kernel(const float* __restrict__ xyz,
                                                       const float* __restrict__ points,
                                                       const float* __restrict__ w0,
                                                       int* __restrict__ fidx,
                                                       unsigned short* __restrict__ T) {
    if (blockIdx.x >= 16) {
        // ---------------- T path: T[b][n][o] = sum_c w0[o][c]*feat ----
        for (int chunk = blockIdx.x - 16; chunk < 256; chunk += 240) {
            int gid = chunk * 256 + threadIdx.x;   // b*4096 + n
            int b = gid >> 12, n = gid & (NN - 1);
            const float* xb = xyz + (size_t)b * 3 * NN;
            const float* pb = points + (size_t)b * 64 * NN;
            float acc[64];
#pragma unroll
            for (int o = 0; o < 64; o++) acc[o] = 0.f;
            for (int c = 0; c < 67; c++) {
                float v = (c < 3) ? xb[c * NN + n] : pb[(c - 3) * NN + n];
#pragma unroll
                for (int o = 0; o < 64; o++) acc[o] = fmaf(v, w0[o * 67 + c], acc[o]);
            }
            unsigned short* dst = T + (size_t)gid * 64;
            for (int oo = 0; oo < 64; oo += 8) {
                union { unsigned short u[8]; uint4 v; } r;
#pragma unroll
                for (int j = 0; j < 8; j++) r.u[j] = f2bf(acc[oo + j]);
                *(uint4*)&dst[oo] = r.v;
            }
        }
        return;
    }
    // ---------------- FPS path ----------------
    int b = blockIdx.x, tid = threadIdx.x;
    const float* xb = xyz + (size_t)b * 3 * NN;
    __shared__ float4 sxyz4[NN];                    // 64 KB winner-xyz cache
    __shared__ unsigned long long redk[2][4];       // parity x wave keys
    __shared__ float4 redc[2][4];                   // parity x wave candidate xyz
    __shared__ int fbuf[NP];                        // result staging (LDS)
    float px[16], py[16], pz[16], dist[16];
#pragma unroll
    for (int i = 0; i < 16; i++) {
        int n = i * 256 + tid;
        px[i] = xb[n]; py[i] = xb[NN + n]; pz[i] = xb[2 * NN + n];
        sxyz4[n] = make_float4(px[i], py[i], pz[i], 0.f);
        dist[i] = 1e10f;
    }
    // Pin coords in VGPRs: opaque redefinition defeats rematerialization.
#pragma unroll
    for (int i = 0; i < 16; i++) {
        asm volatile("" : "+v"(px[i]));
        asm volatile("" : "+v"(py[i]));
        asm volatile("" : "+v"(pz[i]));
    }
    int wv = tid >> 6;
    if (tid == 0) {
        // prime parity-0 slots: winner = point 0 (key low32 = ~0 -> far=0)
        redk[0][0] = ~0ull; redk[0][1] = 0ull; redk[0][2] = 0ull; redk[0][3] = 0ull;
        redc[0][0] = make_float4(px[0], py[0], pz[0], 0.f);  // tid0 i=0 -> n=0
    }
    __syncthreads();
    for (int t = 0; t < NP; t++) {
        int p = t & 1;
        // one parallel LDS round: 4 keys + 4 candidate xyz (all uniform)
        ulonglong2 ka = *(ulonglong2*)&redk[p][0];
        ulonglong2 kb = *(ulonglong2*)&redk[p][2];
        float4 c0 = redc[p][0], c1 = redc[p][1];
        float4 c2 = redc[p][2], c3 = redc[p][3];
        unsigned long long k0 = ka.x, k1 = ka.y, k2 = kb.x, k3 = kb.y;
        if (k1 > k0) { k0 = k1; c0 = c1; }
        if (k3 > k2) { k2 = k3; c2 = c3; }
        if (k2 > k0) { k0 = k2; c0 = c2; }
        int far = (int)(~(unsigned)k0);
        if (tid == 0) fbuf[t] = far;
        float cx = c0.x, cy = c0.y, cz = c0.z;
        // distance update (exact, no fma)
        float tv[16]; int ti[16];
#pragma unroll
        for (int i = 0; i < 16; i++) {
            float dx = __fsub_rn(px[i], cx);
            float dy = __fsub_rn(py[i], cy);
            float dz = __fsub_rn(pz[i], cz);
            float d = __fadd_rn(__fadd_rn(__fmul_rn(dx, dx), __fmul_rn(dy, dy)),
                                __fmul_rn(dz, dz));
            float nd = fminf(dist[i], d);
            dist[i] = nd;
            tv[i] = nd; ti[i] = i;
        }
        // thread-local argmax tree, tie -> lowest i (= lowest n)
#pragma unroll
        for (int s = 1; s < 16; s <<= 1) {
#pragma unroll
            for (int i = 0; i < 16; i += 2 * s) {
                if (tv[i + s] > tv[i]) { tv[i] = tv[i + s]; ti[i] = ti[i + s]; }
            }
        }
        int n_best = ti[0] * 256 + tid;
        unsigned long long k =
            ((unsigned long long)__float_as_uint(tv[0]) << 32) |
            (unsigned long long)(~(unsigned)n_best);
        k = dppmax<0x111, 0xf>(k);   // row_shr:1
        k = dppmax<0x112, 0xf>(k);   // row_shr:2
        k = dppmax<0x114, 0xf>(k);   // row_shr:4
        k = dppmax<0x118, 0xf>(k);   // row_shr:8
        k = dppmax<0x142, 0xa>(k);   // row_bcast:15
        k = dppmax<0x143, 0xc>(k);   // row_bcast:31
        if ((tid & 63) == 63) {      // publish next-iteration candidate
            int nwin = (int)(~(unsigned)k);
            redk[p ^ 1][wv] = k;
            redc[p ^ 1][wv] = sxyz4[nwin];
        }
        __syncthreads();
    }
    for (int i = tid; i < NP; i += 256) fidx[b * NP + i] = fbuf[i];
}

// =====================================================================
// K2 (fused): query_ball + new_xyz output + BN1 stats + (last block)
// BN1 finalize. qball exact: sqr=(sa+sb)-2*dot, dot=((x*cx+y*cy)+z*cz),
// compare sqr > 0.04f -> exclude; first 32 ascending, pad with first.
// =====================================================================
__global__ __launch_bounds__(256) void group_kernel(const float* __restrict__ xyz,
                                                    const unsigned short* __restrict__ T,
                                                    const int* __restrict__ fidx,
                                                    int* __restrict__ idx,
                                                    const float* __restrict__ w0,
                                                    const float* __restrict__ b0,
                                                    double* __restrict__ stage1,
                                                    float* __restrict__ out0,
                                                    const float* __restrict__ gamma,
                                                    const float* __restrict__ beta,
                                                    float* __restrict__ AB,
                                                    unsigned* __restrict__ ctr) {
    __shared__ int gidx[4][NS];
    __shared__ int lastf;
    int t = threadIdx.x, wv = t >> 6, lane = t & 63;
    int g = blockIdx.x * 4 + wv;
    int b = g >> 10, s = g & 1023;
    const float* xb = xyz + (size_t)b * 3 * NN;
    int fid = fidx[g];
    float cx = xb[fid], cy = xb[NN + fid], cz = xb[2 * NN + fid];
    if (lane < 3) {
        float v = (lane == 0) ? cx : ((lane == 1) ? cy : cz);
        out0[((size_t)b * 3 + lane) * NP + s] = v;
    }
    float sa = __fadd_rn(__fadd_rn(__fmul_rn(cx, cx), __fmul_rn(cy, cy)),
                         __fmul_rn(cz, cz));
    int* out = idx + (size_t)g * NS;
    int total = 0; int first = 0;
    for (int ci = 0; ci < NN / 64; ci++) {
        int n = ci * 64 + lane;
        float x = xb[n], y = xb[NN + n], z = xb[2 * NN + n];
        float sb = __fadd_rn(__fadd_rn(__fmul_rn(x, x), __fmul_rn(y, y)),
                             __fmul_rn(z, z));
        float dot = __fadd_rn(__fadd_rn(__fmul_rn(x, cx), __fmul_rn(y, cy)),
                              __fmul_rn(z, cz));
        float sqr = __fsub_rn(__fadd_rn(sa, sb), __fmul_rn(2.0f, dot));
        bool pred = !(sqr > 0.04f);
        unsigned long long mask = __ballot(pred);
        if (mask) {
            if (total == 0) first = ci * 64 + (int)__builtin_ctzll(mask);
            int pos = total + (int)__popcll(mask & ((1ull << lane) - 1ull));
            if (pred && pos < NS) { out[pos] = n; gidx[wv][pos] = n; }
            total += (int)__popcll(mask);
            if (total >= NS) break;
        }
    }
    if (total < NS) {
        if (lane >= total && lane < NS) { out[lane] = first; gidx[wv][lane] = first; }
    }
    // ---- BN1 stats: lane = channel o ----
    int o = lane;
    float uo = fmaf(w0[o * 67 + 2], cz, fmaf(w0[o * 67 + 1], cy, w0[o * 67] * cx));
    float bo = b0[o];
    const unsigned short* Tb = T + (size_t)b * NN * 64;
    float s1 = 0.f, s2 = 0.f;
    for (int k = 0; k < NS; k++) {
        int n = gidx[wv][k];
        float tv = bf2f(Tb[(size_t)n * 64 + o]);
        float h = tv - uo + bo;
        s1 += h; s2 = fmaf(h, h, s2);
    }
    int slot = g & 63;
    atomicAdd(&stage1[slot * 128 + o], (double)s1);
    atomicAdd(&stage1[slot * 128 + 64 + o], (double)s2);
    // ---- last block finalizes BN1 (A=g/sqrt(v+eps), B=bt-m*A) ----
    __syncthreads();   // drains this block's atomics (vmcnt at barrier)
    if (t == 0) {
        unsigned prev = __hip_atomic_fetch_add(ctr, 1u, __ATOMIC_ACQ_REL,
                                               __HIP_MEMORY_SCOPE_AGENT);
        lastf = (prev == (unsigned)(NGRP / 4 - 1));
    }
    __syncthreads();
    if (lastf && t < 64) {
        double ss = 0.0, q = 0.0;
        for (int i = 0; i < 64; i++) {
            ss += __hip_atomic_load(&stage1[i * 128 + t], __ATOMIC_RELAXED,
                                    __HIP_MEMORY_SCOPE_AGENT);
            q  += __hip_atomic_load(&stage1[i * 128 + 64 + t], __ATOMIC_RELAXED,
                                    __HIP_MEMORY_SCOPE_AGENT);
        }
        double m = ss * (1.0 / CNT);
        double v = q * (1.0 / CNT) - m * m;
        double A = (double)gamma[t] / sqrt(v + 1e-5);
        AB[t] = (float)A;
        AB[64 + t] = (float)((double)beta[t] - m * A);
    }
}

// =====================================================================
// K5: layer2 MFMA. Block = 4 waves = 4 groups. Per group:
// C[k=32][o2=64] = A[k][o=64] x B[o][o2], 16x16x32 bf16 MFMA:
// 2 m-tiles x 4 n-tiles x 2 K-steps = 16 MFMA/wave. Last block
// finalizes BN2.
// =====================================================================
__global__ __launch_bounds__(256) void layer2_kernel(const float* __restrict__ xyz,
                                                     const unsigned short* __restrict__ T,
                                                     const int* __restrict__ fidx,
                                                     const int* __restrict__ idx,
                                                     const float* __restrict__ w0,
                                                     const float* __restrict__ b0,
                                                     const float* __restrict__ AB1,
                                                     const float* __restrict__ w1,
                                                     const float* __restrict__ b1,
                                                     unsigned short* __restrict__ h2,
                                                     double* __restrict__ stage2,
                                                     const float* __restrict__ gamma,
                                                     const float* __restrict__ beta,
                                                     float* __restrict__ AB2out,
                                                     unsigned* __restrict__ ctr) {
    __shared__ __attribute__((aligned(16))) unsigned short w1s[64][72];     // [o2][o]
    __shared__ __attribute__((aligned(16))) unsigned short h1s[4][32][72];  // [wv][k][o]
    __shared__ float psum[64], psq[64];
    __shared__ int lastf;
    int t = threadIdx.x, wv = t >> 6, lane = t & 63;
    int quad = lane >> 4, col = lane & 15;
    int g = blockIdx.x * 4 + wv;
    int b = g >> 10;
    for (int lin = t; lin < 4096; lin += 256)
        w1s[lin >> 6][lin & 63] = f2bf(w1[lin]);
    if (t < 64) { psum[t] = 0.f; psq[t] = 0.f; }
    {   // phase1: rebuild normalized h1 (bf16) into LDS [k][o], lane = o
        int fid = fidx[g];
        const float* xb = xyz + (size_t)b * 3 * NN;
        float cx = xb[fid], cy = xb[NN + fid], cz = xb[2 * NN + fid];
        int o = lane;
        float uo = fmaf(w0[o * 67 + 2], cz, fmaf(w0[o * 67 + 1], cy, w0[o * 67] * cx));
        float bo = b0[o];
        float a1 = AB1[o], bb1 = AB1[64 + o];
        const int* gi = idx + (size_t)g * NS;
        const unsigned short* Tb = T + (size_t)b * NN * 64;
        for (int k = 0; k < NS; k++) {
            int n = gi[k];
            float tv = bf2f(Tb[(size_t)n * 64 + o]);
            float h = tv - uo + bo;
            float hn = fmaxf(fmaf(h, a1, bb1), 0.f);
            h1s[wv][k][o] = f2bf(hn);
        }
    }
    __syncthreads();
    // ---- MFMA: 2 mt x 4 nt x 2 ks ----
    f32x4 acc[2][4];
#pragma unroll
    for (int i = 0; i < 2; i++)
#pragma unroll
        for (int j = 0; j < 4; j++) acc[i][j] = (f32x4){0.f, 0.f, 0.f, 0.f};
#pragma unroll
    for (int ks = 0; ks < 2; ks++) {
        bf16x8 a0 = as_bf(*(const uint4*)&h1s[wv][col][ks * 32 + quad * 8]);
        bf16x8 a1f = as_bf(*(const uint4*)&h1s[wv][16 + col][ks * 32 + quad * 8]);
#pragma unroll
        for (int nt = 0; nt < 4; nt++) {
            bf16x8 bf = as_bf(*(const uint4*)&w1s[nt * 16 + col][ks * 32 + quad * 8]);
            acc[0][nt] = __builtin_amdgcn_mfma_f32_16x16x32_bf16(a0, bf, acc[0][nt], 0, 0, 0);
            acc[1][nt] = __builtin_amdgcn_mfma_f32_16x16x32_bf16(a1f, bf, acc[1][nt], 0, 0, 0);
        }
    }
    // ---- epilogue: + b1, BN2 stats, restage C (bf16) into h1s ----
    float s1[4], s2[4];
#pragma unroll
    for (int nt = 0; nt < 4; nt++) {
        float bb = b1[nt * 16 + col];
        s1[nt] = 0.f; s2[nt] = 0.f;
#pragma unroll
        for (int mt = 0; mt < 2; mt++)
#pragma unroll
            for (int r = 0; r < 4; r++) {
                float v = acc[mt][nt][r] + bb;
                s1[nt] += v; s2[nt] = fmaf(v, v, s2[nt]);
                h1s[wv][mt * 16 + quad * 4 + r][nt * 16 + col] = f2bf(v);
            }
        s1[nt] += __shfl_xor(s1[nt], 16); s1[nt] += __shfl_xor(s1[nt], 32);
        s2[nt] += __shfl_xor(s2[nt], 16); s2[nt] += __shfl_xor(s2[nt], 32);
        if (quad == 0) {
            atomicAdd(&psum[nt * 16 + col], s1[nt]);
            atomicAdd(&psq[nt * 16 + col], s2[nt]);
        }
    }
    // ---- h2 global store: coalesced uint4 rows from LDS ----
#pragma unroll
    for (int r = 0; r < 4; r++) {
        int lin = lane + 64 * r;
        int row = lin >> 3, c = lin & 7;
        uint4 v = *(const uint4*)&h1s[wv][row][c * 8];
        *(uint4*)&h2[((size_t)g * NS + row) * 64 + c * 8] = v;
    }
    __syncthreads();
    if (t < 64) {
        int slot = blockIdx.x & 63;
        atomicAdd(&stage2[slot * 128 + t], (double)psum[t]);
        atomicAdd(&stage2[slot * 128 + 64 + t], (double)psq[t]);
    }
    __syncthreads();
    if (t == 0) {
        unsigned prev = __hip_atomic_fetch_add(ctr, 1u, __ATOMIC_ACQ_REL,
                                               __HIP_MEMORY_SCOPE_AGENT);
        lastf = (prev == (unsigned)(NGRP / 4 - 1));
    }
    __syncthreads();
    if (lastf && t < 64) {
        double ss = 0.0, q = 0.0;
        for (int i = 0; i < 64; i++) {
            ss += __hip_atomic_load(&stage2[i * 128 + t], __ATOMIC_RELAXED,
                                    __HIP_MEMORY_SCOPE_AGENT);
            q  += __hip_atomic_load(&stage2[i * 128 + 64 + t], __ATOMIC_RELAXED,
                                    __HIP_MEMORY_SCOPE_AGENT);
        }
        double m = ss * (1.0 / CNT);
        double v = q * (1.0 / CNT) - m * m;
        double A = (double)gamma[t] / sqrt(v + 1e-5);
        AB2out[t] = (float)A;
        AB2out[64 + t] = (float)((double)beta[t] - m * A);
    }
}

// =====================================================================
// K7: layer3 MFMA (64->128): h3 = h2n @ w2^T + b2. 2mt x 8nt x 2ks =
// 32 MFMA/wave. Emits BN3 partial sums + per-(g,o3) max/min of h3
// (BN3+relu is monotone per sign of a3 -> no 2nd GEMM pass needed).
// Last block finalizes BN3.
// =====================================================================
__global__ __launch_bounds__(256) void layer3_kernel(const unsigned short* __restrict__ h2,
                                                     const float* __restrict__ AB2,
                                                     const float* __restrict__ w2,
                                                     const float* __restrict__ b2,
                                                     double* __restrict__ stage3,
                                                     float* __restrict__ mxbuf,
                                                     float* __restrict__ mnbuf,
                                                     const float* __restrict__ gamma,
                                                     const float* __restrict__ beta,
                                                     float* __restrict__ AB3out,
                                                     unsigned* __restrict__ ctr) {
    __shared__ __attribute__((aligned(16))) unsigned short w2s[128][72];    // [o3][o2]
    __shared__ __attribute__((aligned(16))) unsigned short h2s[4][32][72];  // [wv][k][o2]
    __shared__ float psum[128], psq[128];
    __shared__ int lastf;
    int t = threadIdx.x, wv = t >> 6, lane = t & 63;
    int quad = lane >> 4, col = lane & 15;
    int g = blockIdx.x * 4 + wv;
    for (int lin = t; lin < 8192; lin += 256)
        w2s[lin >> 6][lin & 63] = f2bf(w2[lin]);
    if (t < 128) { psum[t] = 0.f; psq[t] = 0.f; }
    {   // phase1: h2 -> BN2+relu -> LDS bf16. lane owns channels c*8..c*8+7
        int c = lane & 7;
        float a2v[8], bb2v[8];
#pragma unroll
        for (int j = 0; j < 8; j++) {
            a2v[j] = AB2[c * 8 + j];
            bb2v[j] = AB2[64 + c * 8 + j];
        }
        const unsigned short* hg = h2 + (size_t)g * NS * 64;
#pragma unroll
        for (int r = 0; r < 4; r++) {
            int row = (lane >> 3) + 8 * r;
            union { uint4 v; unsigned short u[8]; } in, outp;
            in.v = *(const uint4*)&hg[row * 64 + c * 8];
#pragma unroll
            for (int j = 0; j < 8; j++) {
                float f = bf2f(in.u[j]);
                outp.u[j] = f2bf(fmaxf(fmaf(f, a2v[j], bb2v[j]), 0.f));
            }
            *(uint4*)&h2s[wv][row][c * 8] = outp.v;
        }
    }
    __syncthreads();
    // ---- MFMA: 2 mt x 8 nt x 2 ks ----
    f32x4 acc[2][8];
#pragma unroll
    for (int i = 0; i < 2; i++)
#pragma unroll
        for (int j = 0; j < 8; j++) acc[i][j] = (f32x4){0.f, 0.f, 0.f, 0.f};
#pragma unroll
    for (int ks = 0; ks < 2; ks++) {
        bf16x8 a0 = as_bf(*(const uint4*)&h2s[wv][col][ks * 32 + quad * 8]);
        bf16x8 a1f = as_bf(*(const uint4*)&h2s[wv][16 + col][ks * 32 + quad * 8]);
#pragma unroll
        for (int nt = 0; nt < 8; nt++) {
            bf16x8 bf = as_bf(*(const uint4*)&w2s[nt * 16 + col][ks * 32 + quad * 8]);
            acc[0][nt] = __builtin_amdgcn_mfma_f32_16x16x32_bf16(a0, bf, acc[0][nt], 0, 0, 0);
            acc[1][nt] = __builtin_amdgcn_mfma_f32_16x16x32_bf16(a1f, bf, acc[1][nt], 0, 0, 0);
        }
    }
    // ---- epilogue: + b2, BN3 stats + per-o3 max/min over k ----
#pragma unroll
    for (int nt = 0; nt < 8; nt++) {
        float bb = b2[nt * 16 + col];
        float s1 = 0.f, s2 = 0.f, mx = -1e30f, mn = 1e30f;
#pragma unroll
        for (int mt = 0; mt < 2; mt++)
#pragma unroll
            for (int r = 0; r < 4; r++) {
                float v = acc[mt][nt][r] + bb;
                s1 += v; s2 = fmaf(v, v, s2);
                mx = fmaxf(mx, v); mn = fminf(mn, v);
            }
        s1 += __shfl_xor(s1, 16); s1 += __shfl_xor(s1, 32);
        s2 += __shfl_xor(s2, 16); s2 += __shfl_xor(s2, 32);
        mx = fmaxf(mx, __shfl_xor(mx, 16)); mx = fmaxf(mx, __shfl_xor(mx, 32));
        mn = fminf(mn, __shfl_xor(mn, 16)); mn = fminf(mn, __shfl_xor(mn, 32));
        if (quad == 0) {
            atomicAdd(&psum[nt * 16 + col], s1);
            atomicAdd(&psq[nt * 16 + col], s2);
            mxbuf[(size_t)g * 128 + nt * 16 + col] = mx;
            mnbuf[(size_t)g * 128 + nt * 16 + col] = mn;
        }
    }
    __syncthreads();
    if (t < 128) {
        int slot = blockIdx.x & 63;
        atomicAdd(&stage3[slot * 256 + t], (double)psum[t]);
        atomicAdd(&stage3[slot * 256 + 128 + t], (double)psq[t]);
    }
    __syncthreads();
    if (t == 0) {
        unsigned prev = __hip_atomic_fetch_add(ctr, 1u, __ATOMIC_ACQ_REL,
                                               __HIP_MEMORY_SCOPE_AGENT);
        lastf = (prev == (unsigned)(NGRP / 4 - 1));
    }
    __syncthreads();
    if (lastf && t < 128) {
        double ss = 0.0, q = 0.0;
        for (int i = 0; i < 64; i++) {
            ss += __hip_atomic_load(&stage3[i * 256 + t], __ATOMIC_RELAXED,
                                    __HIP_MEMORY_SCOPE_AGENT);
            q  += __hip_atomic_load(&stage3[i * 256 + 128 + t], __ATOMIC_RELAXED,
                                    __HIP_MEMORY_SCOPE_AGENT);
        }
        double m = ss * (1.0 / CNT);
        double v = q * (1.0 / CNT) - m * m;
        double A = (double)gamma[t] / sqrt(v + 1e-5);
        AB3out[t] = (float)A;
        AB3out[128 + t] = (float)((double)beta[t] - m * A);
    }
}

// =====================================================================
// K9: epilogue. out1[b][o][s] = relu(a3*sel+b3), sel = a3>=0?max:min.
// Coalesced read [s][o] -> LDS -> coalesced transposed write [o][s].
// =====================================================================
__global__ __launch_bounds__(256) void epilogue_kernel(const float* __restrict__ mxbuf,
                                                       const float* __restrict__ mnbuf,
                                                       const float* __restrict__ AB3,
                                                       float* __restrict__ out1) {
    __shared__ float tile[32][65];
    int blk = blockIdx.x;
    int b = blk >> 6; int rem = blk & 63;
    int o0 = (rem >> 4) * 32; int s0 = (rem & 15) * 64;
    int t = threadIdx.x;
#pragma unroll
    for (int j = 0; j < 8; j++) {
        int lin = t + 256 * j;
        int sl = lin >> 5, ol = lin & 31;
        int o = o0 + ol;
        float a = AB3[o], bb = AB3[128 + o];
        size_t src = ((size_t)b * NP + s0 + sl) * 128 + o;
        float v = (a >= 0.f) ? mxbuf[src] : mnbuf[src];
        tile[ol][sl] = fmaxf(fmaf(v, a, bb), 0.f);
    }
    __syncthreads();
#pragma unroll
    for (int j = 0; j < 8; j++) {
        int lin = t + 256 * j;
        int ol = lin >> 6, sl = lin & 63;
        out1[((size_t)b * 128 + o0 + ol) * NP + s0 + sl] = tile[ol][sl];
    }
}

// =====================================================================
extern "C" void kernel_launch(void* const* d_in, const int* in_sizes, int n_in,
                              void* d_out, int out_size, void* d_ws, size_t ws_size,
                              hipStream_t stream) {
    const float* xyz    = (const float*)d_in[0];
    const float* points = (const float*)d_in[1];
    const float* w0  = (const float*)d_in[2];
    const float* b0  = (const float*)d_in[3];
    const float* g0  = (const float*)d_in[4];
    const float* bt0 = (const float*)d_in[5];
    const float* w1  = (const float*)d_in[6];
    const float* b1  = (const float*)d_in[7];
    const float* g1  = (const float*)d_in[8];
    const float* bt1 = (const float*)d_in[9];
    const float* w2  = (const float*)d_in[10];
    const float* b2  = (const float*)d_in[11];
    const float* g2  = (const float*)d_in[12];
    const float* bt2 = (const float*)d_in[13];

    char* ws = (char*)d_ws;
    // workspace layout (bytes, 256-aligned): total ~94.7 MB
    int*            fidx = (int*)(ws + 0);                       //   64 KB
    int*            idx  = (int*)(ws + 65536);                   //    2 MB
    unsigned short* T    = (unsigned short*)(ws + 2162688);      //  8.4 MB bf16
    unsigned short* h2   = (unsigned short*)(ws + 10551296);     //   67 MB bf16
    float*          mxbuf = (float*)(ws + 77660160);             //  8.4 MB
    float*          mnbuf = (float*)(ws + 86048768);             //  8.4 MB
    double*         stage = (double*)(ws + 94437376);            //  256 KB
    unsigned*       ctrs  = (unsigned*)(ws + 94437376 + 262144); //  256 B
    float*          AB   = (float*)(ws + 94437376 + 262400);     //    2 KB
    double* stage1 = stage;
    double* stage2 = stage + 64 * 128;
    double* stage3 = stage + 2 * 64 * 128;
    float* AB1 = AB; float* AB2 = AB + 128; float* AB3 = AB + 256;
    float* out0 = (float*)d_out;
    float* out1 = out0 + NB * 3 * NP;

    hipMemsetAsync(stage, 0, 262144 + 256, stream);   // zero stats + counters

    fps_t_kernel<<<256, 256, 0, stream>>>(xyz, points, w0, fidx, T);
    group_kernel<<<NGRP / 4, 256, 0, stream>>>(xyz, T, fidx, idx, w0, b0, stage1,
                                               out0, g0, bt0, AB1, ctrs + 0);
    layer2_kernel<<<NGRP / 4, 256, 0, stream>>>(xyz, T, fidx, idx, w0, b0, AB1,
                                                w1, b1, h2, stage2,
                                                g1, bt1, AB2, ctrs + 1);
    layer3_kernel<<<NGRP / 4, 256, 0, stream>>>(h2, AB2, w2, b2, stage3, mxbuf, mnbuf,
                                                g2, bt2, AB3, ctrs + 2);
    epilogue_kernel<<<1024, 256, 0, stream>>>(mxbuf, mnbuf, AB3, out1);
}

// Round 8
// 829.971 us; speedup vs baseline: 1.4976x; 1.4976x over previous
//
#include <hip/hip_runtime.h>
#include <stdint.h>

// Problem constants
#define NB    16
#define NN    4096
#define NP    1024
#define NS    32
#define NGRP  (NB*NP)          // 16384 groups
#define CNT   524288.0         // B*K*S elements per channel for BN stats

typedef short  bf16x8 __attribute__((ext_vector_type(8)));
typedef float  f32x4  __attribute__((ext_vector_type(4)));

// ---------- bf16 helpers (RNE) ----------
__device__ __forceinline__ float bf2f(unsigned short u) {
    return __uint_as_float(((unsigned)u) << 16);
}
__device__ __forceinline__ unsigned short f2bf(float f) {
    unsigned u = __float_as_uint(f);
    unsigned r = u + 0x7fffu + ((u >> 16) & 1u);
    return (unsigned short)(r >> 16);
}
__device__ __forceinline__ bf16x8 as_bf(uint4 u) {
    union { uint4 a; bf16x8 b; } c; c.a = u; return c.b;
}

// u64 max with one DPP step (compare-select). VALU-only.
template <int CTRL, int RM>
__device__ __forceinline__ unsigned long long dppmax(unsigned long long k) {
    int lo = (int)(unsigned)k;
    int hi = (int)(k >> 32);
    int ml = __builtin_amdgcn_update_dpp(lo, lo, CTRL, RM, 0xf, false);
    int mh = __builtin_amdgcn_update_dpp(hi, hi, CTRL, RM, 0xf, false);
    unsigned long long m = ((unsigned long long)(unsigned)mh << 32) | (unsigned)ml;
    return m > k ? m : k;
}

// =====================================================================
// K1 (fused): blocks 0..15 = FPS (one per batch), blocks 16..271 = the
// per-point transform T (runs on otherwise-idle CUs under FPS's shadow).
// FPS: 256 thr x 16 pts, exact arithmetic (no fma, ((xx+yy)+zz) order),
// key=(dist_bits<<32)|~n packs exact argmax-tie-lowest into u64 max.
// Round-8: FPS is VALU-ISSUE-bound (VALUBusy ~68% on FPS CUs, r7 PMC).
// Argmax is a running best fused into the update loop (strict > keeps
// lowest i = lowest n) — kills the tv/ti copy arrays + 15-node tree.
// =====================================================================
__global__ __launch_bounds__(256, 1) void fps_t_kernel(const float* __restrict__ xyz,
                                                       const float* __restrict__ points,
                                                       const float* __restrict__ w0,
                                                       int* __restrict__ fidx,
                                                       unsigned short* __restrict__ T) {
    if (blockIdx.x >= 16) {
        // ---------------- T path: T[b][n][o] = sum_c w0[o][c]*feat ----
        int gid = (blockIdx.x - 16) * 256 + threadIdx.x;   // b*4096 + n
        int b = gid >> 12, n = gid & (NN - 1);
        const float* xb = xyz + (size_t)b * 3 * NN;
        const float* pb = points + (size_t)b * 64 * NN;
        float acc[64];
#pragma unroll
        for (int o = 0; o < 64; o++) acc[o] = 0.f;
        for (int c = 0; c < 67; c++) {
            float v = (c < 3) ? xb[c * NN + n] : pb[(c - 3) * NN + n];
#pragma unroll
            for (int o = 0; o < 64; o++) acc[o] = fmaf(v, w0[o * 67 + c], acc[o]);
        }
        unsigned short* dst = T + (size_t)gid * 64;
        for (int oo = 0; oo < 64; oo += 8) {
            union { unsigned short u[8]; uint4 v; } r;
#pragma unroll
            for (int j = 0; j < 8; j++) r.u[j] = f2bf(acc[oo + j]);
            *(uint4*)&dst[oo] = r.v;
        }
        return;
    }
    // ---------------- FPS path ----------------
    int b = blockIdx.x, tid = threadIdx.x;
    const float* xb = xyz + (size_t)b * 3 * NN;
    __shared__ float4 sxyz4[NN];                    // 64 KB centroid cache
    __shared__ unsigned long long red[2][4];        // parity x wave slots
    __shared__ int fbuf[NP];                        // result staging (LDS)
    float px[16], py[16], pz[16], dist[16];
#pragma unroll
    for (int i = 0; i < 16; i++) {
        int n = i * 256 + tid;
        px[i] = xb[n]; py[i] = xb[NN + n]; pz[i] = xb[2 * NN + n];
        sxyz4[n] = make_float4(px[i], py[i], pz[i], 0.f);
        dist[i] = 1e10f;
    }
    // Pin coords in VGPRs: opaque redefinition defeats rematerialization.
#pragma unroll
    for (int i = 0; i < 16; i++) {
        asm volatile("" : "+v"(px[i]));
        asm volatile("" : "+v"(py[i]));
        asm volatile("" : "+v"(pz[i]));
    }
    int wv = tid >> 6;
    if (tid == 0) fbuf[0] = 0;
    int far = 0;
    __syncthreads();
    for (int t = 0; t < NP; t++) {
        float4 c = sxyz4[far];                       // one ds_read_b128
        float cx = c.x, cy = c.y, cz = c.z;
        // distance update + fused running argmax (strict > keeps lowest i)
        float bv = -1.0f; int bi = 0;
#pragma unroll
        for (int i = 0; i < 16; i++) {
            float dx = __fsub_rn(px[i], cx);
            float dy = __fsub_rn(py[i], cy);
            float dz = __fsub_rn(pz[i], cz);
            float d = __fadd_rn(__fadd_rn(__fmul_rn(dx, dx), __fmul_rn(dy, dy)),
                                __fmul_rn(dz, dz));
            float nd = fminf(dist[i], d);
            dist[i] = nd;
            if (nd > bv) { bv = nd; bi = i; }        // cmp + 2 cndmask (i inline)
        }
        int n_best = bi * 256 + tid;
        unsigned long long k =
            ((unsigned long long)__float_as_uint(bv) << 32) |
            (unsigned long long)(~(unsigned)n_best);
        k = dppmax<0x111, 0xf>(k);   // row_shr:1
        k = dppmax<0x112, 0xf>(k);   // row_shr:2
        k = dppmax<0x114, 0xf>(k);   // row_shr:4
        k = dppmax<0x118, 0xf>(k);   // row_shr:8
        k = dppmax<0x142, 0xa>(k);   // row_bcast:15
        k = dppmax<0x143, 0xc>(k);   // row_bcast:31
        if ((tid & 63) == 63) red[t & 1][wv] = k;
        __syncthreads();
        ulonglong2 ra = *(ulonglong2*)&red[t & 1][0];
        ulonglong2 rb = *(ulonglong2*)&red[t & 1][2];
        unsigned long long r0 = ra.x, r1 = ra.y, r2 = rb.x, r3 = rb.y;
        if (r1 > r0) r0 = r1;
        if (r3 > r2) r2 = r3;
        if (r2 > r0) r0 = r2;
        far = (int)(~(unsigned)r0);   // low32 = ~n -> n
        if (tid == 0 && t + 1 < NP) fbuf[t + 1] = far;
    }
    __syncthreads();
    for (int i = tid; i < NP; i += 256) fidx[b * NP + i] = fbuf[i];
}

// =====================================================================
// K2 (fused): query_ball + new_xyz output + BN1 stats. One wave per
// group. qball exact: sqr=(sa+sb)-2*dot, dot=((x*cx+y*cy)+z*cz),
// compare sqr > 0.04f -> exclude; first 32 ascending, pad with first.
// =====================================================================
__global__ __launch_bounds__(256) void group_kernel(const float* __restrict__ xyz,
                                                    const unsigned short* __restrict__ T,
                                                    const int* __restrict__ fidx,
                                                    int* __restrict__ idx,
                                                    const float* __restrict__ w0,
                                                    const float* __restrict__ b0,
                                                    double* __restrict__ stage1,
                                                    float* __restrict__ out0) {
    __shared__ int gidx[4][NS];
    int t = threadIdx.x, wv = t >> 6, lane = t & 63;
    int g = blockIdx.x * 4 + wv;
    int b = g >> 10, s = g & 1023;
    const float* xb = xyz + (size_t)b * 3 * NN;
    int fid = fidx[g];
    float cx = xb[fid], cy = xb[NN + fid], cz = xb[2 * NN + fid];
    if (lane < 3) {
        float v = (lane == 0) ? cx : ((lane == 1) ? cy : cz);
        out0[((size_t)b * 3 + lane) * NP + s] = v;
    }
    float sa = __fadd_rn(__fadd_rn(__fmul_rn(cx, cx), __fmul_rn(cy, cy)),
                         __fmul_rn(cz, cz));
    int* out = idx + (size_t)g * NS;
    int total = 0; int first = 0;
    for (int ci = 0; ci < NN / 64; ci++) {
        int n = ci * 64 + lane;
        float x = xb[n], y = xb[NN + n], z = xb[2 * NN + n];
        float sb = __fadd_rn(__fadd_rn(__fmul_rn(x, x), __fmul_rn(y, y)),
                             __fmul_rn(z, z));
        float dot = __fadd_rn(__fadd_rn(__fmul_rn(x, cx), __fmul_rn(y, cy)),
                              __fmul_rn(z, cz));
        float sqr = __fsub_rn(__fadd_rn(sa, sb), __fmul_rn(2.0f, dot));
        bool pred = !(sqr > 0.04f);
        unsigned long long mask = __ballot(pred);
        if (mask) {
            if (total == 0) first = ci * 64 + (int)__builtin_ctzll(mask);
            int pos = total + (int)__popcll(mask & ((1ull << lane) - 1ull));
            if (pred && pos < NS) { out[pos] = n; gidx[wv][pos] = n; }
            total += (int)__popcll(mask);
            if (total >= NS) break;
        }
    }
    if (total < NS) {
        if (lane >= total && lane < NS) { out[lane] = first; gidx[wv][lane] = first; }
    }
    // ---- BN1 stats: lane = channel o ----
    int o = lane;
    float uo = fmaf(w0[o * 67 + 2], cz, fmaf(w0[o * 67 + 1], cy, w0[o * 67] * cx));
    float bo = b0[o];
    const unsigned short* Tb = T + (size_t)b * NN * 64;
    float s1 = 0.f, s2 = 0.f;
    for (int k = 0; k < NS; k++) {
        int n = gidx[wv][k];
        float tv = bf2f(Tb[(size_t)n * 64 + o]);
        float h = tv - uo + bo;
        s1 += h; s2 = fmaf(h, h, s2);
    }
    int slot = g & 63;
    atomicAdd(&stage1[slot * 128 + o], (double)s1);
    atomicAdd(&stage1[slot * 128 + 64 + o], (double)s2);
}

// =====================================================================
// Finalize BN stats: AB[o]=A=g/sqrt(v+eps), AB[C+o]=B=bt-m*A
// =====================================================================
__global__ void finalize_kernel(const double* __restrict__ stage, int C,
                                const float* __restrict__ gamma,
                                const float* __restrict__ beta,
                                float* __restrict__ AB) {
    int o = threadIdx.x;
    double s = 0.0, q = 0.0;
    for (int i = 0; i < 64; i++) {
        s += stage[i * 2 * C + o];
        q += stage[i * 2 * C + C + o];
    }
    double m = s * (1.0 / CNT);
    double v = q * (1.0 / CNT) - m * m;
    double A = (double)gamma[o] / sqrt(v + 1e-5);
    AB[o] = (float)A;
    AB[C + o] = (float)((double)beta[o] - m * A);
}

// =====================================================================
// K5: layer2 MFMA. Block = 4 waves = 4 groups. Per group:
// C[k=32][o2=64] = A[k][o=64] x B[o][o2], 16x16x32 bf16 MFMA:
// 2 m-tiles x 4 n-tiles x 2 K-steps = 16 MFMA/wave.
// =====================================================================
__global__ __launch_bounds__(256) void layer2_kernel(const float* __restrict__ xyz,
                                                     const unsigned short* __restrict__ T,
                                                     const int* __restrict__ fidx,
                                                     const int* __restrict__ idx,
                                                     const float* __restrict__ w0,
                                                     const float* __restrict__ b0,
                                                     const float* __restrict__ AB1,
                                                     const float* __restrict__ w1,
                                                     const float* __restrict__ b1,
                                                     unsigned short* __restrict__ h2,
                                                     double* __restrict__ stage2) {
    __shared__ __attribute__((aligned(16))) unsigned short w1s[64][72];     // [o2][o]
    __shared__ __attribute__((aligned(16))) unsigned short h1s[4][32][72];  // [wv][k][o]
    __shared__ float psum[64], psq[64];
    int t = threadIdx.x, wv = t >> 6, lane = t & 63;
    int quad = lane >> 4, col = lane & 15;
    int g = blockIdx.x * 4 + wv;
    int b = g >> 10;
    for (int lin = t; lin < 4096; lin += 256)
        w1s[lin >> 6][lin & 63] = f2bf(w1[lin]);
    if (t < 64) { psum[t] = 0.f; psq[t] = 0.f; }
    {   // phase1: rebuild normalized h1 (bf16) into LDS [k][o], lane = o
        int fid = fidx[g];
        const float* xb = xyz + (size_t)b * 3 * NN;
        float cx = xb[fid], cy = xb[NN + fid], cz = xb[2 * NN + fid];
        int o = lane;
        float uo = fmaf(w0[o * 67 + 2], cz, fmaf(w0[o * 67 + 1], cy, w0[o * 67] * cx));
        float bo = b0[o];
        float a1 = AB1[o], bb1 = AB1[64 + o];
        const int* gi = idx + (size_t)g * NS;
        const unsigned short* Tb = T + (size_t)b * NN * 64;
        for (int k = 0; k < NS; k++) {
            int n = gi[k];
            float tv = bf2f(Tb[(size_t)n * 64 + o]);
            float h = tv - uo + bo;
            float hn = fmaxf(fmaf(h, a1, bb1), 0.f);
            h1s[wv][k][o] = f2bf(hn);
        }
    }
    __syncthreads();
    // ---- MFMA: 2 mt x 4 nt x 2 ks ----
    f32x4 acc[2][4];
#pragma unroll
    for (int i = 0; i < 2; i++)
#pragma unroll
        for (int j = 0; j < 4; j++) acc[i][j] = (f32x4){0.f, 0.f, 0.f, 0.f};
#pragma unroll
    for (int ks = 0; ks < 2; ks++) {
        bf16x8 a0 = as_bf(*(const uint4*)&h1s[wv][col][ks * 32 + quad * 8]);
        bf16x8 a1f = as_bf(*(const uint4*)&h1s[wv][16 + col][ks * 32 + quad * 8]);
#pragma unroll
        for (int nt = 0; nt < 4; nt++) {
            bf16x8 bf = as_bf(*(const uint4*)&w1s[nt * 16 + col][ks * 32 + quad * 8]);
            acc[0][nt] = __builtin_amdgcn_mfma_f32_16x16x32_bf16(a0, bf, acc[0][nt], 0, 0, 0);
            acc[1][nt] = __builtin_amdgcn_mfma_f32_16x16x32_bf16(a1f, bf, acc[1][nt], 0, 0, 0);
        }
    }
    // ---- epilogue: + b1, BN2 stats, restage C (bf16) into h1s ----
    float s1[4], s2[4];
#pragma unroll
    for (int nt = 0; nt < 4; nt++) {
        float bb = b1[nt * 16 + col];
        s1[nt] = 0.f; s2[nt] = 0.f;
#pragma unroll
        for (int mt = 0; mt < 2; mt++)
#pragma unroll
            for (int r = 0; r < 4; r++) {
                float v = acc[mt][nt][r] + bb;
                s1[nt] += v; s2[nt] = fmaf(v, v, s2[nt]);
                h1s[wv][mt * 16 + quad * 4 + r][nt * 16 + col] = f2bf(v);
            }
        s1[nt] += __shfl_xor(s1[nt], 16); s1[nt] += __shfl_xor(s1[nt], 32);
        s2[nt] += __shfl_xor(s2[nt], 16); s2[nt] += __shfl_xor(s2[nt], 32);
        if (quad == 0) {
            atomicAdd(&psum[nt * 16 + col], s1[nt]);
            atomicAdd(&psq[nt * 16 + col], s2[nt]);
        }
    }
    // ---- h2 global store: coalesced uint4 rows from LDS ----
#pragma unroll
    for (int r = 0; r < 4; r++) {
        int lin = lane + 64 * r;
        int row = lin >> 3, c = lin & 7;
        uint4 v = *(const uint4*)&h1s[wv][row][c * 8];
        *(uint4*)&h2[((size_t)g * NS + row) * 64 + c * 8] = v;
    }
    __syncthreads();
    if (t < 64) {
        int slot = blockIdx.x & 63;
        atomicAdd(&stage2[slot * 128 + t], (double)psum[t]);
        atomicAdd(&stage2[slot * 128 + 64 + t], (double)psq[t]);
    }
}

// =====================================================================
// K7: layer3 MFMA (64->128): h3 = h2n @ w2^T + b2. 2mt x 8nt x 2ks =
// 32 MFMA/wave. Emits BN3 partial sums + per-(g,o3) max/min of h3
// (BN3+relu is monotone per sign of a3 -> no 2nd GEMM pass needed).
// =====================================================================
__global__ __launch_bounds__(256) void layer3_kernel(const unsigned short* __restrict__ h2,
                                                     const float* __restrict__ AB2,
                                                     const float* __restrict__ w2,
                                                     const float* __restrict__ b2,
                                                     double* __restrict__ stage3,
                                                     float* __restrict__ mxbuf,
                                                     float* __restrict__ mnbuf) {
    __shared__ __attribute__((aligned(16))) unsigned short w2s[128][72];    // [o3][o2]
    __shared__ __attribute__((aligned(16))) unsigned short h2s[4][32][72];  // [wv][k][o2]
    __shared__ float psum[128], psq[128];
    int t = threadIdx.x, wv = t >> 6, lane = t & 63;
    int quad = lane >> 4, col = lane & 15;
    int g = blockIdx.x * 4 + wv;
    for (int lin = t; lin < 8192; lin += 256)
        w2s[lin >> 6][lin & 63] = f2bf(w2[lin]);
    if (t < 128) { psum[t] = 0.f; psq[t] = 0.f; }
    {   // phase1: h2 -> BN2+relu -> LDS bf16. lane owns channels c*8..c*8+7
        int c = lane & 7;
        float a2v[8], bb2v[8];
#pragma unroll
        for (int j = 0; j < 8; j++) {
            a2v[j] = AB2[c * 8 + j];
            bb2v[j] = AB2[64 + c * 8 + j];
        }
        const unsigned short* hg = h2 + (size_t)g * NS * 64;
#pragma unroll
        for (int r = 0; r < 4; r++) {
            int row = (lane >> 3) + 8 * r;
            union { uint4 v; unsigned short u[8]; } in, outp;
            in.v = *(const uint4*)&hg[row * 64 + c * 8];
#pragma unroll
            for (int j = 0; j < 8; j++) {
                float f = bf2f(in.u[j]);
                outp.u[j] = f2bf(fmaxf(fmaf(f, a2v[j], bb2v[j]), 0.f));
            }
            *(uint4*)&h2s[wv][row][c * 8] = outp.v;
        }
    }
    __syncthreads();
    // ---- MFMA: 2 mt x 8 nt x 2 ks ----
    f32x4 acc[2][8];
#pragma unroll
    for (int i = 0; i < 2; i++)
#pragma unroll
        for (int j = 0; j < 8; j++) acc[i][j] = (f32x4){0.f, 0.f, 0.f, 0.f};
#pragma unroll
    for (int ks = 0; ks < 2; ks++) {
        bf16x8 a0 = as_bf(*(const uint4*)&h2s[wv][col][ks * 32 + quad * 8]);
        bf16x8 a1f = as_bf(*(const uint4*)&h2s[wv][16 + col][ks * 32 + quad * 8]);
#pragma unroll
        for (int nt = 0; nt < 8; nt++) {
            bf16x8 bf = as_bf(*(const uint4*)&w2s[nt * 16 + col][ks * 32 + quad * 8]);
            acc[0][nt] = __builtin_amdgcn_mfma_f32_16x16x32_bf16(a0, bf, acc[0][nt], 0, 0, 0);
            acc[1][nt] = __builtin_amdgcn_mfma_f32_16x16x32_bf16(a1f, bf, acc[1][nt], 0, 0, 0);
        }
    }
    // ---- epilogue: + b2, BN3 stats + per-o3 max/min over k ----
#pragma unroll
    for (int nt = 0; nt < 8; nt++) {
        float bb = b2[nt * 16 + col];
        float s1 = 0.f, s2 = 0.f, mx = -1e30f, mn = 1e30f;
#pragma unroll
        for (int mt = 0; mt < 2; mt++)
#pragma unroll
            for (int r = 0; r < 4; r++) {
                float v = acc[mt][nt][r] + bb;
                s1 += v; s2 = fmaf(v, v, s2);
                mx = fmaxf(mx, v); mn = fminf(mn, v);
            }
        s1 += __shfl_xor(s1, 16); s1 += __shfl_xor(s1, 32);
        s2 += __shfl_xor(s2, 16); s2 += __shfl_xor(s2, 32);
        mx = fmaxf(mx, __shfl_xor(mx, 16)); mx = fmaxf(mx, __shfl_xor(mx, 32));
        mn = fminf(mn, __shfl_xor(mn, 16)); mn = fminf(mn, __shfl_xor(mn, 32));
        if (quad == 0) {
            atomicAdd(&psum[nt * 16 + col], s1);
            atomicAdd(&psq[nt * 16 + col], s2);
            mxbuf[(size_t)g * 128 + nt * 16 + col] = mx;
            mnbuf[(size_t)g * 128 + nt * 16 + col] = mn;
        }
    }
    __syncthreads();
    if (t < 128) {
        int slot = blockIdx.x & 63;
        atomicAdd(&stage3[slot * 256 + t], (double)psum[t]);
        atomicAdd(&stage3[slot * 256 + 128 + t], (double)psq[t]);
    }
}

// =====================================================================
// K9: epilogue. out1[b][o][s] = relu(a3*sel+b3), sel = a3>=0?max:min.
// Coalesced read [s][o] -> LDS -> coalesced transposed write [o][s].
// =====================================================================
__global__ __launch_bounds__(256) void epilogue_kernel(const float* __restrict__ mxbuf,
                                                       const float* __restrict__ mnbuf,
                                                       const float* __restrict__ AB3,
                                                       float* __restrict__ out1) {
    __shared__ float tile[32][65];
    int blk = blockIdx.x;
    int b = blk >> 6; int rem = blk & 63;
    int o0 = (rem >> 4) * 32; int s0 = (rem & 15) * 64;
    int t = threadIdx.x;
#pragma unroll
    for (int j = 0; j < 8; j++) {
        int lin = t + 256 * j;
        int sl = lin >> 5, ol = lin & 31;
        int o = o0 + ol;
        float a = AB3[o], bb = AB3[128 + o];
        size_t src = ((size_t)b * NP + s0 + sl) * 128 + o;
        float v = (a >= 0.f) ? mxbuf[src] : mnbuf[src];
        tile[ol][sl] = fmaxf(fmaf(v, a, bb), 0.f);
    }
    __syncthreads();
#pragma unroll
    for (int j = 0; j < 8; j++) {
        int lin = t + 256 * j;
        int ol = lin >> 6, sl = lin & 63;
        out1[((size_t)b * 128 + o0 + ol) * NP + s0 + sl] = tile[ol][sl];
    }
}

// =====================================================================
extern "C" void kernel_launch(void* const* d_in, const int* in_sizes, int n_in,
                              void* d_out, int out_size, void* d_ws, size_t ws_size,
                              hipStream_t stream) {
    const float* xyz    = (const float*)d_in[0];
    const float* points = (const float*)d_in[1];
    const float* w0  = (const float*)d_in[2];
    const float* b0  = (const float*)d_in[3];
    const float* g0  = (const float*)d_in[4];
    const float* bt0 = (const float*)d_in[5];
    const float* w1  = (const float*)d_in[6];
    const float* b1  = (const float*)d_in[7];
    const float* g1  = (const float*)d_in[8];
    const float* bt1 = (const float*)d_in[9];
    const float* w2  = (const float*)d_in[10];
    const float* b2  = (const float*)d_in[11];
    const float* g2  = (const float*)d_in[12];
    const float* bt2 = (const float*)d_in[13];

    char* ws = (char*)d_ws;
    // workspace layout (bytes, 256-aligned): total ~94.7 MB
    int*            fidx = (int*)(ws + 0);                       //   64 KB
    int*            idx  = (int*)(ws + 65536);                   //    2 MB
    unsigned short* T    = (unsigned short*)(ws + 2162688);      //  8.4 MB bf16
    unsigned short* h2   = (unsigned short*)(ws + 10551296);     //   67 MB bf16
    float*          mxbuf = (float*)(ws + 77660160);             //  8.4 MB
    float*          mnbuf = (float*)(ws + 86048768);             //  8.4 MB
    double*         stage = (double*)(ws + 94437376);            //  256 KB
    float*          AB   = (float*)(ws + 94699520);              //    2 KB
    double* stage1 = stage;
    double* stage2 = stage + 64 * 128;
    double* stage3 = stage + 2 * 64 * 128;
    float* AB1 = AB; float* AB2 = AB + 128; float* AB3 = AB + 256;
    float* out0 = (float*)d_out;
    float* out1 = out0 + NB * 3 * NP;

    hipMemsetAsync(stage, 0, 262144, stream);   // zero stat slots

    fps_t_kernel<<<16 + 256, 256, 0, stream>>>(xyz, points, w0, fidx, T);
    group_kernel<<<NGRP / 4, 256, 0, stream>>>(xyz, T, fidx, idx, w0, b0, stage1, out0);
    finalize_kernel<<<1, 64, 0, stream>>>(stage1, 64, g0, bt0, AB1);
    layer2_kernel<<<NGRP / 4, 256, 0, stream>>>(xyz, T, fidx, idx, w0, b0, AB1,
                                                w1, b1, h2, stage2);
    finalize_kernel<<<1, 64, 0, stream>>>(stage2, 64, g1, bt1, AB2);
    layer3_kernel<<<NGRP / 4, 256, 0, stream>>>(h2, AB2, w2, b2, stage3, mxbuf, mnbuf);
    finalize_kernel<<<1, 128, 0, stream>>>(stage3, 128, g2, bt2, AB3);
    epilogue_kernel<<<1024, 256, 0, stream>>>(mxbuf, mnbuf, AB3, out1);
}